// Round 2
// baseline (238.526 us; speedup 1.0000x reference)
//
#include <hip/hip_runtime.h>
#include <math.h>

#define C_CH 128
#define HW 128
#define KK 5
#define PAD 2
#define TILE_ROWS 64
#define LDS_ROWS (TILE_ROWS + 2*PAD)   // 68
#define LDS_COLS (HW + 2*PAD)          // 132
#define NW (KK*KK*C_CH + C_CH)         // 3328 weights per sample

__global__ __launch_bounds__(256, 4) void hyperconv_dw_silu(
    const float* __restrict__ inp, const float* __restrict__ wts,
    float* __restrict__ out)
{
    __shared__ float s[LDS_ROWS][LDS_COLS];

    const int tid  = threadIdx.x;
    const int tile = blockIdx.x;   // row strip: 0..(HW/TILE_ROWS-1)
    const int c    = blockIdx.y;   // channel
    const int b    = blockIdx.z;   // batch

    // Block-uniform weights -> scalar loads / SGPRs
    const float* wt = wts + (size_t)b * NW;
    float wk[25];
    #pragma unroll
    for (int j = 0; j < 25; ++j) wk[j] = wt[c * 25 + j];
    const float bias = wt[KK*KK*C_CH + c];

    const int row0 = tile * TILE_ROWS;
    const float* plane = inp + ((size_t)(b * C_CH + c)) * (HW * HW);

    // 1) zero the 4 halo columns (cols 0,1,130,131) for ALL 68 rows.
    //    272 items > 256 threads -> strided loop (was the round-1 bug).
    for (int i = tid; i < LDS_ROWS * 4; i += 256) {
        int r  = i >> 2;
        int ci = i & 3;
        int col = (ci < 2) ? ci : (HW + ci);   // 0,1,130,131
        s[r][col] = 0.0f;
    }

    // 2) interior load: 68 rows x 32 float4 segments, coalesced 16B/lane
    for (int idx = tid; idx < LDS_ROWS * (HW / 4); idx += 256) {
        int r  = idx >> 5;          // / 32
        int cs = idx & 31;          // float4 segment within row
        int gr = row0 - PAD + r;    // global input row
        float4 v = make_float4(0.f, 0.f, 0.f, 0.f);
        if (gr >= 0 && gr < HW) {
            v = *(const float4*)(plane + (size_t)gr * HW + cs * 4);
        }
        // LDS col = 2 + 4*cs  (even -> 8B aligned): two float2 writes
        float2* dst = (float2*)&s[r][2 + cs * 4];
        dst[0] = make_float2(v.x, v.y);
        dst[1] = make_float2(v.z, v.w);
    }
    __syncthreads();

    const int colg = tid & 31;   // 32 col-groups of 4 output cols
    const int rowg = tid >> 5;   // 8 row-groups
    float* oplane = out + ((size_t)(b * C_CH + c)) * (HW * HW);

    #pragma unroll
    for (int p = 0; p < 2; ++p) {
        const int ro = p * 32 + rowg * 4;   // local output row base (0..60)

        float acc[4][4];
        #pragma unroll
        for (int i = 0; i < 4; ++i)
            #pragma unroll
            for (int j = 0; j < 4; ++j)
                acc[i][j] = bias;

        #pragma unroll
        for (int r = 0; r < 8; ++r) {
            // window row: output row ro+orow reads LDS rows ro+orow+kh, kh=0..4
            // LDS cols 4*colg .. 4*colg+7 (16B aligned -> 2x ds_read_b128)
            const float4 a  = *(const float4*)&s[ro + r][colg * 4];
            const float4 bb = *(const float4*)&s[ro + r][colg * 4 + 4];
            float x[8] = {a.x, a.y, a.z, a.w, bb.x, bb.y, bb.z, bb.w};

            #pragma unroll
            for (int orow = 0; orow < 4; ++orow) {
                const int kh = r - orow;            // tap row
                if (kh < 0 || kh > 4) continue;     // resolved at compile time
                #pragma unroll
                for (int oc = 0; oc < 4; ++oc) {
                    #pragma unroll
                    for (int kw = 0; kw < 5; ++kw) {
                        acc[orow][oc] = fmaf(wk[kh * 5 + kw], x[oc + kw], acc[orow][oc]);
                    }
                }
            }
        }

        // epilogue: SiLU + coalesced float4 stores
        #pragma unroll
        for (int orow = 0; orow < 4; ++orow) {
            float4 o;
            float v0 = acc[orow][0], v1 = acc[orow][1], v2 = acc[orow][2], v3 = acc[orow][3];
            o.x = v0 / (1.0f + expf(-v0));
            o.y = v1 / (1.0f + expf(-v1));
            o.z = v2 / (1.0f + expf(-v2));
            o.w = v3 / (1.0f + expf(-v3));
            *(float4*)(oplane + (size_t)(row0 + ro + orow) * HW + colg * 4) = o;
        }
    }
}

extern "C" void kernel_launch(void* const* d_in, const int* in_sizes, int n_in,
                              void* d_out, int out_size, void* d_ws, size_t ws_size,
                              hipStream_t stream) {
    const float* inp = (const float*)d_in[0];
    const float* wts = (const float*)d_in[1];
    float* out = (float*)d_out;

    const int batch = in_sizes[1] / NW;   // 16
    dim3 grid(HW / TILE_ROWS, C_CH, batch);
    hyperconv_dw_silu<<<grid, 256, 0, stream>>>(inp, wts, out);
}